// Round 1
// baseline (720.901 us; speedup 1.0000x reference)
//
#include <hip/hip_runtime.h>

typedef unsigned short u16;
typedef unsigned int   u32;

using bf16x8 = __attribute__((ext_vector_type(8))) __bf16;
using f32x4  = __attribute__((ext_vector_type(4))) float;

__device__ __forceinline__ float bf2f(u16 h){ return __uint_as_float(((u32)h) << 16); }
__device__ __forceinline__ u16 f2bf(float f){
    u32 u = __float_as_uint(f);
    u32 r = u + 0x7FFFu + ((u >> 16) & 1u);   // round-to-nearest-even
    return (u16)(r >> 16);
}

// ---------------------------------------------------------------------------
// Device-side dtype probe.
// flags[0]: 1 if float tensors are bf16, 0 if fp32 (probed from x ~ N(0,1)).
// flags[1]: mask dtype: 0=u8/bool, 1=int32, 2=bf16, 3=fp32.
// ---------------------------------------------------------------------------
__global__ void probe_dtypes(const void* x, const void* masks, int* flags)
{
    if (blockIdx.x != 0 || threadIdx.x != 0) return;
    const u16* hx = (const u16*)x;
    int cnt = 0;
    for (int i = 0; i < 128; i++){
        int e = (hx[i] >> 7) & 0xFF;          // bf16 exponent field position
        if (e >= 100 && e <= 140) cnt++;       // plausible for N(0,1) bf16
    }
    // bf16 data: ~128/128 hit. fp32 data: only odd halfwords (~74/128).
    flags[0] = (cnt >= 100) ? 1 : 0;

    const u32* w  = (const u32*)masks;
    const u16* hm = (const u16*)masks;
    int i32ok = 1, f32ok = 1, bf16ok = 1;
    for (int i = 0; i < 64; i++){
        u32 v = w[i];
        if (v > 1u) i32ok = 0;
        if (v != 0u && v != 0x3F800000u) f32ok = 0;
    }
    for (int i = 0; i < 128; i++){
        u16 h = hm[i];
        if (h != 0 && h != 0x3F80) bf16ok = 0;
    }
    int md = 0;
    if (i32ok) md = 1; else if (f32ok) md = 3; else if (bf16ok) md = 2;
    flags[1] = md;
}

// ---------------------------------------------------------------------------
// Transpose + convert to bf16: dst[j*ldd + i] = cvt(src[i*J + j]), 3 matrices
// selected by blockIdx.z. Write extent = grid.x*32 rows (may exceed J; rows
// j>=J are written as 0 -> zero padding for GEMM tiles). Dims I, J exact
// multiples of 32 in the i / grid sense (I always; J guarded).
// ---------------------------------------------------------------------------
__global__ void trans_cvt_f3(const void* s0, const void* s1, const void* s2,
                             u16* dst, size_t dstride, int I, int J, int ldd,
                             const int* flags)
{
    __shared__ float tile[32][33];
    const void* src = (blockIdx.z == 0) ? s0 : (blockIdx.z == 1) ? s1 : s2;
    u16* d = dst + (size_t)blockIdx.z * dstride;
    int j0 = blockIdx.x * 32, i0 = blockIdx.y * 32;
    int tx = threadIdx.x, ty = threadIdx.y;
    bool isbf = (flags[0] != 0);
    #pragma unroll
    for (int s = 0; s < 32; s += 8){
        int i = i0 + ty + s, j = j0 + tx;
        float v = 0.f;
        if (j < J){
            size_t idx = (size_t)i * J + j;
            v = isbf ? bf2f(((const u16*)src)[idx]) : ((const float*)src)[idx];
        }
        tile[ty + s][tx] = v;
    }
    __syncthreads();
    #pragma unroll
    for (int s = 0; s < 32; s += 8){
        int j = j0 + ty + s, i = i0 + tx;
        d[(size_t)j * ldd + i] = f2bf(tile[tx][ty + s]);
    }
}

// ---------------------------------------------------------------------------
// masks [P][NN] (dtype per flags[1]) -> mfT [n][p] bf16 {0,1}, zero-padded to
// the full write extent (grid.x*32 cols x grid.y*32 rows).
// ---------------------------------------------------------------------------
__global__ void trans_mask(const void* src, u16* dst, int P_, int NN_, int ldd,
                           const int* flags)
{
    __shared__ u16 tile[32][33];
    int p0 = blockIdx.x * 32, n0 = blockIdx.y * 32;
    int tx = threadIdx.x, ty = threadIdx.y;
    int md = flags[1];
    #pragma unroll
    for (int s = 0; s < 32; s += 8){
        int p = p0 + ty + s, n = n0 + tx;
        u16 v = 0;
        if (p < P_ && n < NN_){
            size_t idx = (size_t)p * NN_ + n;
            bool on;
            if (md == 0)      on = ((const unsigned char*)src)[idx] != 0;
            else if (md == 1) on = ((const int*)src)[idx] != 0;
            else if (md == 2) on = ((const u16*)src)[idx] != 0;
            else              on = ((const float*)src)[idx] != 0.f;
            v = on ? (u16)0x3F80 : (u16)0;   // bf16 1.0 / 0.0
        }
        tile[ty + s][tx] = v;
    }
    __syncthreads();
    #pragma unroll
    for (int s = 0; s < 32; s += 8){
        int n = n0 + ty + s, p = p0 + tx;
        dst[(size_t)n * ldd + p] = tile[tx][ty + s];
    }
}

__global__ void pack_biases(const void* a0, const void* a1, const void* a2,
                            const void* c0, const void* c1, const void* c2,
                            float* b1f, float* b2f, const int* flags)
{
    int idx = blockIdx.x * 256 + threadIdx.x;
    if (idx >= 3072) return;
    int k = idx >> 10, r = idx & 1023;
    bool isbf = (flags[0] != 0);
    const void* p1 = (k == 0) ? a0 : (k == 1) ? a1 : a2;
    const void* p2 = (k == 0) ? c0 : (k == 1) ? c1 : c2;
    b1f[idx] = isbf ? bf2f(((const u16*)p1)[r]) : ((const float*)p1)[r];
    b2f[idx] = isbf ? bf2f(((const u16*)p2)[r]) : ((const float*)p2)[r];
}

__global__ void count_rows(const u16* mfT, float* counts, int ldd, int Pfull)
{
    int n = blockIdx.x;
    const u16* row = mfT + (size_t)n * ldd;
    int s = 0;
    for (int p = threadIdx.x; p < Pfull; p += 256) s += (row[p] != 0);
    __shared__ int red[256];
    red[threadIdx.x] = s;
    __syncthreads();
    for (int st = 128; st > 0; st >>= 1){
        if (threadIdx.x < st) red[threadIdx.x] += red[threadIdx.x + st];
        __syncthreads();
    }
    if (threadIdx.x == 0) counts[n] = (float)red[0];
}

// ---------------------------------------------------------------------------
// NT GEMM: C[M][N] = A[M][K] . B[N][K]^T, bf16 in, fp32 accumulate.
// Both operands K-contiguous -> identical conflict-free staging.
// BM=BN=128, BK=32, 256 threads (4 waves), wave = 64x64 via 4x4 of 16x16x32.
// LDS stride 40 bf16 (80 B): 16B-aligned rows, <=2-way bank aliasing.
// BIAS_MODE: 0 none, 1 bias[m], 2 bias[n]. Split-K via blockIdx.z + kChunk
// (ATOMIC=true accumulates with atomicAdd into pre-zeroed fp32 C).
// ---------------------------------------------------------------------------
template<int BIAS_MODE, bool RELU, bool OUT_BF16, bool ATOMIC>
__global__ __launch_bounds__(256)
void gemm_nt(const u16* __restrict__ A, int lda,
             const u16* __restrict__ B, int ldb,
             void* __restrict__ Cp, int ldc,
             const float* __restrict__ bias,
             int kIters, int kChunk)
{
    constexpr int LDT = 40;
    __shared__ u16 As[128 * LDT];
    __shared__ u16 Bs[128 * LDT];

    const int tid  = threadIdx.x;
    const int wave = tid >> 6;
    const int lane = tid & 63;
    const int wr = wave >> 1, wc = wave & 1;
    const int t = lane & 15, q = lane >> 4;
    const int m0 = blockIdx.y * 128;
    const int n0 = blockIdx.x * 128;

    int k0 = blockIdx.z * kChunk;
    int k1 = k0 + kChunk; if (k1 > kIters) k1 = kIters;
    if (k0 >= k1) return;

    f32x4 acc[4][4];
    #pragma unroll
    for (int a = 0; a < 4; a++)
        #pragma unroll
        for (int b = 0; b < 4; b++)
            #pragma unroll
            for (int e = 0; e < 4; e++) acc[a][b][e] = 0.f;

    for (int kt = k0; kt < k1; ++kt){
        __syncthreads();
        #pragma unroll
        for (int i = 0; i < 2; i++){
            int c = tid + i * 256;            // 512 16B-chunks per tile
            int row = c >> 2, pos = c & 3;
            const uint4* ga = reinterpret_cast<const uint4*>(
                A + (size_t)(m0 + row) * lda + (size_t)kt * 32) + pos;
            const uint4* gb = reinterpret_cast<const uint4*>(
                B + (size_t)(n0 + row) * ldb + (size_t)kt * 32) + pos;
            uint4 va = *ga;
            uint4 vb = *gb;
            *reinterpret_cast<uint4*>(&As[row * LDT + pos * 8]) = va;
            *reinterpret_cast<uint4*>(&Bs[row * LDT + pos * 8]) = vb;
        }
        __syncthreads();
        bf16x8 af[4], bg[4];
        #pragma unroll
        for (int mi = 0; mi < 4; mi++)
            af[mi] = *reinterpret_cast<const bf16x8*>(
                &As[(wr * 64 + mi * 16 + t) * LDT + q * 8]);
        #pragma unroll
        for (int ni = 0; ni < 4; ni++)
            bg[ni] = *reinterpret_cast<const bf16x8*>(
                &Bs[(wc * 64 + ni * 16 + t) * LDT + q * 8]);
        #pragma unroll
        for (int mi = 0; mi < 4; mi++)
            #pragma unroll
            for (int ni = 0; ni < 4; ni++)
                acc[mi][ni] = __builtin_amdgcn_mfma_f32_16x16x32_bf16(
                    af[mi], bg[ni], acc[mi][ni], 0, 0, 0);
    }

    // Epilogue. D mapping (m89/m91-verified): col = lane&15, row = q*4 + reg.
    #pragma unroll
    for (int mi = 0; mi < 4; mi++){
        #pragma unroll
        for (int i = 0; i < 4; i++){
            int m = m0 + wr * 64 + mi * 16 + q * 4 + i;
            float bm = 0.f;
            if constexpr (BIAS_MODE == 1) bm = bias[m];
            #pragma unroll
            for (int ni = 0; ni < 4; ni++){
                int n = n0 + wc * 64 + ni * 16 + t;
                float v = acc[mi][ni][i] + bm;
                if constexpr (BIAS_MODE == 2) v += bias[n];
                if constexpr (RELU) v = (v > 0.f) ? v : 0.f;
                size_t ci = (size_t)m * ldc + n;
                if constexpr (ATOMIC)        atomicAdd(((float*)Cp) + ci, v);
                else if constexpr (OUT_BF16) ((u16*)Cp)[ci] = f2bf(v);
                else                         ((float*)Cp)[ci] = v;
            }
        }
    }
}

// means[k][n][q] = bf16( sums[n][k*1024+q] / count[n] ), zero for pad rows.
__global__ void build_means(const float* sums, const float* counts, u16* means)
{
    int b = blockIdx.x;            // 0 .. 3*384-1
    int k = b / 384, n = b % 384;
    float inv = 0.f;
    if (n < 300){ float c = counts[n]; inv = (c > 0.f) ? 1.f / c : 0.f; }
    size_t obase = ((size_t)k * 384 + n) * 1024;
    size_t sbase = (size_t)n * 3072 + (size_t)k * 1024;
    #pragma unroll
    for (int i = 0; i < 4; i++){
        int qi = threadIdx.x + i * 256;
        float v = (n < 300) ? sums[sbase + qi] * inv : 0.f;
        means[obase + qi] = f2bf(v);
    }
}

__global__ void select_out(const float* out_all, const int* labels, void* dout,
                           const int* flags)
{
    int idx = blockIdx.x * 256 + threadIdx.x;   // < 300*1024
    int n = idx >> 10, r = idx & 1023;
    int lab = labels[n];
    float v = out_all[((size_t)lab * 384 + (size_t)n) * 1024 + r];
    if (flags[0]) ((u16*)dout)[idx] = f2bf(v);
    else          ((float*)dout)[idx] = v;
}

// ---------------------------------------------------------------------------
extern "C" void kernel_launch(void* const* d_in, const int* in_sizes, int n_in,
                              void* d_out, int out_size, void* d_ws, size_t ws_size,
                              hipStream_t stream)
{
    constexpr int C = 256, R = 1024, NN = 300, P = 40000;
    constexpr int PPAD = 40064;          // 313 * 128
    constexpr int M1 = 3 * R;            // 3072 (k-major packed L1 outputs)
    constexpr int MN = 384;              // node rows padded to 3*128

    const void* x     = d_in[0];
    const void* masks = d_in[1];
    const int*  labels = (const int*)d_in[2];
    const void* W1[3] = { d_in[3], d_in[7],  d_in[11] };
    const void* B1[3] = { d_in[4], d_in[8],  d_in[12] };
    const void* W2[3] = { d_in[5], d_in[9],  d_in[13] };
    const void* B2[3] = { d_in[6], d_in[10], d_in[14] };
    (void)in_sizes; (void)n_in; (void)out_size;

    char* ws = (char*)d_ws;
    size_t off = 0;
    auto alloc = [&](size_t b)->size_t {
        size_t o = off; off += (b + 255) & ~(size_t)255; return o;
    };

    int*   flags  = (int*)  (ws + alloc(256));
    u16*   feat   = (u16*)  (ws + alloc((size_t)PPAD * C * 2));   // [p][c]
    u16*   B1T    = (u16*)  (ws + alloc((size_t)M1 * C * 2));     // [k*R+r][c]
    float* b1f    = (float*)(ws + alloc((size_t)M1 * 4));
    float* b2f    = (float*)(ws + alloc((size_t)M1 * 4));
    u16*   mfT    = (u16*)  (ws + alloc((size_t)MN * PPAD * 2));  // [n][p]
    float* sums   = (float*)(ws + alloc((size_t)MN * M1 * 4));    // [n][k*R+r]
    float* counts = (float*)(ws + alloc((size_t)MN * 4));
    u16*   means  = (u16*)  (ws + alloc((size_t)3 * MN * R * 2)); // [k][n][q]
    u16*   W2T    = (u16*)  (ws + alloc((size_t)3 * R * R * 2));  // [k][r][q]
    float* outA   = (float*)(ws + alloc((size_t)3 * MN * R * 4)); // [k][n][r]
    u16*   HT     = (u16*)  (ws + off);                           // [k*R+r][p-chunk]

    size_t remain  = (ws_size > off) ? ws_size - off : 0;
    long   maxcols = (long)(remain / ((size_t)M1 * 2));
    maxcols &= ~(long)127;
    if (maxcols > PPAD) maxcols = PPAD;
    if (maxcols < 128)  maxcols = 128;   // below this ws is simply insufficient

    probe_dtypes<<<1, 64, 0, stream>>>(x, masks, flags);
    hipMemsetAsync(sums, 0, (size_t)MN * M1 * 4, stream);

    // feat[p][c] = x[c][p]  (zero-padded rows p in [P, PPAD))
    trans_cvt_f3<<<dim3(PPAD / 32, C / 32, 1), dim3(32, 8), 0, stream>>>(
        x, x, x, feat, 0, C, P, C, flags);
    // B1T[k*R+r][c] = Wk1[c][r]
    trans_cvt_f3<<<dim3(R / 32, C / 32, 3), dim3(32, 8), 0, stream>>>(
        W1[0], W1[1], W1[2], B1T, (size_t)R * C, C, R, C, flags);
    // W2T[k][r][q] = Wk2[q][r]
    trans_cvt_f3<<<dim3(R / 32, R / 32, 3), dim3(32, 8), 0, stream>>>(
        W2[0], W2[1], W2[2], W2T, (size_t)R * R, R, R, R, flags);
    pack_biases<<<(3 * R + 255) / 256, 256, 0, stream>>>(
        B1[0], B1[1], B1[2], B2[0], B2[1], B2[2], b1f, b2f, flags);
    // mfT[n][p] (bf16 {0,1}), zero-padded rows/cols
    trans_mask<<<dim3(PPAD / 32, MN / 32, 1), dim3(32, 8), 0, stream>>>(
        masks, mfT, P, NN, PPAD, flags);
    count_rows<<<NN, 256, 0, stream>>>(mfT, counts, PPAD, PPAD);

    for (long base = 0; base < PPAD; base += maxcols){
        long cols = PPAD - base; if (cols > maxcols) cols = maxcols;
        // L1: HT[m=k*R+r][p] = relu( sum_c B1T[m][c] * feat[p][c] + b1f[m] )
        gemm_nt<1, true, true, false>
            <<<dim3(cols / 128, M1 / 128, 1), 256, 0, stream>>>(
                B1T, C, feat + (size_t)base * C, C, HT, (int)cols, b1f,
                C / 32, C / 32);
        // mask-sum: sums[n][m] += sum_p mfT[n][p] * HT[m][p]
        int iters = (int)(cols / 32);
        int S = 12; if (S > iters) S = iters;
        int kch = (iters + S - 1) / S;
        gemm_nt<0, false, false, true>
            <<<dim3(M1 / 128, MN / 128, S), 256, 0, stream>>>(
                mfT + base, PPAD, HT, (int)cols, sums, M1, nullptr,
                iters, kch);
    }

    build_means<<<3 * MN, 256, 0, stream>>>(sums, counts, means);

    // L2 on means: outA[k][n][r] = sum_q means[k][n][q] * W2T[k][r][q] + b2[k][r]
    for (int k = 0; k < 3; k++){
        gemm_nt<2, false, false, false>
            <<<dim3(R / 128, MN / 128, 1), 256, 0, stream>>>(
                means + (size_t)k * MN * R, R, W2T + (size_t)k * R * R, R,
                outA + (size_t)k * MN * R, R, b2f + (size_t)k * R,
                R / 32, R / 32);
    }

    select_out<<<(NN * R) / 256, 256, 0, stream>>>(outA, labels, d_out, flags);
}

// Round 2
// 597.423 us; speedup vs baseline: 1.2067x; 1.2067x over previous
//
#include <hip/hip_runtime.h>

typedef unsigned short u16;
typedef unsigned int   u32;

using bf16x8 = __attribute__((ext_vector_type(8))) __bf16;
using f32x4  = __attribute__((ext_vector_type(4))) float;

__device__ __forceinline__ float bf2f(u16 h){ return __uint_as_float(((u32)h) << 16); }
__device__ __forceinline__ u16 f2bf(float f){
    u32 u = __float_as_uint(f);
    u32 r = u + 0x7FFFu + ((u >> 16) & 1u);   // round-to-nearest-even
    return (u16)(r >> 16);
}

// async global->LDS, 16B per lane; LDS dest = wave-uniform base + lane*16.
__device__ __forceinline__ void async16(const void* g, void* l){
    __builtin_amdgcn_global_load_lds(
        (const __attribute__((address_space(1))) unsigned int*)g,
        (__attribute__((address_space(3))) unsigned int*)l, 16, 0, 0);
}

// ---------------------------------------------------------------------------
// dtype probe: flags[0]=1 if float tensors bf16 else fp32; flags[1]=mask dtype
// 0=u8/bool,1=i32,2=bf16,3=f32.
// ---------------------------------------------------------------------------
__global__ void probe_dtypes(const void* x, const void* masks, int* flags)
{
    if (blockIdx.x != 0 || threadIdx.x != 0) return;
    const u16* hx = (const u16*)x;
    int cnt = 0;
    for (int i = 0; i < 128; i++){
        int e = (hx[i] >> 7) & 0xFF;
        if (e >= 100 && e <= 140) cnt++;
    }
    flags[0] = (cnt >= 100) ? 1 : 0;

    const u32* w  = (const u32*)masks;
    const u16* hm = (const u16*)masks;
    int i32ok = 1, f32ok = 1, bf16ok = 1;
    for (int i = 0; i < 64; i++){
        u32 v = w[i];
        if (v > 1u) i32ok = 0;
        if (v != 0u && v != 0x3F800000u) f32ok = 0;
    }
    for (int i = 0; i < 128; i++){
        u16 h = hm[i];
        if (h != 0 && h != 0x3F80) bf16ok = 0;
    }
    int md = 0;
    if (i32ok) md = 1; else if (f32ok) md = 3; else if (bf16ok) md = 2;
    flags[1] = md;
}

// ---------------------------------------------------------------------------
// Label grouping: slot_of_node[n] = label*128 + rank (rank<128), else
// 384 + overflow_rank. ovf_flag = #overflow nodes (0 in the expected case).
// ---------------------------------------------------------------------------
__global__ void build_perm(const int* labels, int* slot_of_node, int* ovf_flag)
{
    __shared__ int lab[300];
    __shared__ unsigned char sp[300];
    int t = threadIdx.x;
    if (t < 300) lab[t] = labels[t];
    __syncthreads();
    int r = 0;
    if (t < 300){
        int k = lab[t];
        for (int j = 0; j < t; j++) r += (lab[j] == k);
        sp[t] = (r >= 128) ? 1 : 0;
    }
    __syncthreads();
    if (t < 300){
        if (!sp[t]) slot_of_node[t] = lab[t] * 128 + r;
        else {
            int so = 0;
            for (int j = 0; j < t; j++) so += sp[j];
            slot_of_node[t] = 384 + so;
        }
    }
    if (t == 0){
        int tot = 0;
        for (int j = 0; j < 300; j++) tot += sp[j];
        *ovf_flag = tot;
    }
}

// ---------------------------------------------------------------------------
// Transpose + convert to bf16, 3 sources via blockIdx.z; zero-pads j >= J.
// ---------------------------------------------------------------------------
__global__ void trans_cvt_f3(const void* s0, const void* s1, const void* s2,
                             u16* dst, size_t dstride, int I, int J, int ldd,
                             const int* flags)
{
    __shared__ float tile[32][33];
    const void* src = (blockIdx.z == 0) ? s0 : (blockIdx.z == 1) ? s1 : s2;
    u16* d = dst + (size_t)blockIdx.z * dstride;
    int j0 = blockIdx.x * 32, i0 = blockIdx.y * 32;
    int tx = threadIdx.x, ty = threadIdx.y;
    bool isbf = (flags[0] != 0);
    #pragma unroll
    for (int s = 0; s < 32; s += 8){
        int i = i0 + ty + s, j = j0 + tx;
        float v = 0.f;
        if (j < J){
            size_t idx = (size_t)i * J + j;
            v = isbf ? bf2f(((const u16*)src)[idx]) : ((const float*)src)[idx];
        }
        tile[ty + s][tx] = v;
    }
    __syncthreads();
    #pragma unroll
    for (int s = 0; s < 32; s += 8){
        int j = j0 + ty + s, i = i0 + tx;
        d[(size_t)j * ldd + i] = f2bf(tile[tx][ty + s]);
    }
}

// masks [P][NN] -> mfT[slot][p] bf16 {0,1}, rows permuted by slot_of_node.
__global__ void trans_mask(const void* src, u16* dst, const int* slot_of_node,
                           int P_, int NN_, int ldd, const int* flags)
{
    __shared__ u16 tile[32][33];
    __shared__ int slt[32];
    int p0 = blockIdx.x * 32, n0 = blockIdx.y * 32;
    int tx = threadIdx.x, ty = threadIdx.y;
    int md = flags[1];
    if (ty == 0){
        int n = n0 + tx;
        slt[tx] = (n < NN_) ? slot_of_node[n] : -1;
    }
    #pragma unroll
    for (int s = 0; s < 32; s += 8){
        int p = p0 + ty + s, n = n0 + tx;
        u16 v = 0;
        if (p < P_ && n < NN_){
            size_t idx = (size_t)p * NN_ + n;
            bool on;
            if (md == 0)      on = ((const unsigned char*)src)[idx] != 0;
            else if (md == 1) on = ((const int*)src)[idx] != 0;
            else if (md == 2) on = ((const u16*)src)[idx] != 0;
            else              on = ((const float*)src)[idx] != 0.f;
            v = on ? (u16)0x3F80 : (u16)0;
        }
        tile[ty + s][tx] = v;
    }
    __syncthreads();
    #pragma unroll
    for (int s = 0; s < 32; s += 8){
        int slot = slt[ty + s];
        int p = p0 + tx;
        if (slot >= 0 && p < ldd)
            dst[(size_t)slot * ldd + p] = tile[tx][ty + s];
    }
}

__global__ void pack_biases(const void* a0, const void* a1, const void* a2,
                            const void* c0, const void* c1, const void* c2,
                            float* b1f, float* b2f, const int* flags)
{
    int idx = blockIdx.x * 256 + threadIdx.x;
    if (idx >= 3072) return;
    int k = idx >> 10, r = idx & 1023;
    bool isbf = (flags[0] != 0);
    const void* p1 = (k == 0) ? a0 : (k == 1) ? a1 : a2;
    const void* p2 = (k == 0) ? c0 : (k == 1) ? c1 : c2;
    b1f[idx] = isbf ? bf2f(((const u16*)p1)[r]) : ((const float*)p1)[r];
    b2f[idx] = isbf ? bf2f(((const u16*)p2)[r]) : ((const float*)p2)[r];
}

__global__ void count_rows(const u16* mfT, float* counts, int ldd, int Pfull)
{
    int n = blockIdx.x;
    const u16* row = mfT + (size_t)n * ldd;
    int s = 0;
    for (int p = threadIdx.x; p < Pfull; p += 256) s += (row[p] != 0);
    __shared__ int red[256];
    red[threadIdx.x] = s;
    __syncthreads();
    for (int st = 128; st > 0; st >>= 1){
        if (threadIdx.x < st) red[threadIdx.x] += red[threadIdx.x + st];
        __syncthreads();
    }
    if (threadIdx.x == 0) counts[n] = (float)red[0];
}

// ---------------------------------------------------------------------------
// NT GEMM: C[M][N] = A[M][K] . B[N][K]^T, bf16 in, fp32 acc.
// m97-style staging: global_load_lds width 16, unpadded 64B LDS rows.
// OUT_MODE: 0 f32 store, 1 bf16 via LDS-repack coalesced dwordx4, 2 f32 atomic.
// MAP: 0 normal (y=m,x=n) | 1 swapped (x=m,y=n) | 2 block-diag by label
//      (m0=(bx>>3)*128, n0=bx*128) | 3 batched via blockIdx.z (no split-K).
// ---------------------------------------------------------------------------
template<int BIAS_MODE, bool RELU, int OUT_MODE, int MAP>
__global__ __launch_bounds__(256)
void gemm_nt(const u16* __restrict__ A, int lda,
             const u16* __restrict__ B, int ldb,
             void* __restrict__ Cp, int ldc,
             const float* __restrict__ bias,
             int kIters, int kChunk,
             const int* __restrict__ skipf,
             long abatch, long bbatch, long cbatch, long bbias)
{
    if (skipf && *skipf == 0) return;
    __shared__ __align__(16) u16 sh[8704];   // staging 2x4096; repack 64x136
    u16* As = sh;
    u16* Bs = sh + 4096;

    const int tid  = threadIdx.x;
    const int wave = tid >> 6, lane = tid & 63;
    const int wr = wave >> 1, wc = wave & 1;
    const int t = lane & 15, q = lane >> 4;

    int m0, n0;
    if constexpr (MAP == 1){ m0 = blockIdx.x * 128; n0 = blockIdx.y * 128; }
    else if constexpr (MAP == 2){ m0 = (blockIdx.x >> 3) * 128; n0 = blockIdx.x * 128; }
    else { m0 = blockIdx.y * 128; n0 = blockIdx.x * 128; }

    size_t cofs = 0;
    int k0, k1;
    if constexpr (MAP == 3){
        const int bz = blockIdx.z;
        A += (size_t)bz * (size_t)abatch;
        B += (size_t)bz * (size_t)bbatch;
        bias += (size_t)bz * (size_t)bbias;
        cofs = (size_t)bz * (size_t)cbatch;
        k0 = 0; k1 = kIters;
    } else {
        k0 = blockIdx.z * kChunk;
        k1 = k0 + kChunk; if (k1 > kIters) k1 = kIters;
        if (k0 >= k1) return;
    }

    // staging addresses: chunk = 16 rows x 64B; wave w owns chunks 2w, 2w+1
    const int cr = lane >> 2, cp = lane & 3;
    const int ca = wave * 2, cb = wave * 2 + 1;
    const u16* gA0 = A + (size_t)(m0 + ca * 16 + cr) * lda + cp * 8;
    const u16* gA1 = A + (size_t)(m0 + cb * 16 + cr) * lda + cp * 8;
    const u16* gB0 = B + (size_t)(n0 + ca * 16 + cr) * ldb + cp * 8;
    const u16* gB1 = B + (size_t)(n0 + cb * 16 + cr) * ldb + cp * 8;
    u16* lA0 = As + ca * 512;  u16* lA1 = As + cb * 512;
    u16* lB0 = Bs + ca * 512;  u16* lB1 = Bs + cb * 512;

    f32x4 acc[4][4];
    #pragma unroll
    for (int a = 0; a < 4; a++)
        #pragma unroll
        for (int b = 0; b < 4; b++)
            #pragma unroll
            for (int e = 0; e < 4; e++) acc[a][b][e] = 0.f;

    for (int kt = k0; kt < k1; ++kt){
        __syncthreads();
        const size_t ko = (size_t)kt * 32;
        async16(gA0 + ko, lA0);
        async16(gA1 + ko, lA1);
        async16(gB0 + ko, lB0);
        async16(gB1 + ko, lB1);
        __syncthreads();     // compiler drains vmcnt before s_barrier
        bf16x8 af[4], bg[4];
        #pragma unroll
        for (int mi = 0; mi < 4; mi++)
            af[mi] = *reinterpret_cast<const bf16x8*>(
                &As[(wr * 64 + mi * 16 + t) * 32 + q * 8]);
        #pragma unroll
        for (int ni = 0; ni < 4; ni++)
            bg[ni] = *reinterpret_cast<const bf16x8*>(
                &Bs[(wc * 64 + ni * 16 + t) * 32 + q * 8]);
        #pragma unroll
        for (int mi = 0; mi < 4; mi++)
            #pragma unroll
            for (int ni = 0; ni < 4; ni++)
                acc[mi][ni] = __builtin_amdgcn_mfma_f32_16x16x32_bf16(
                    af[mi], bg[ni], acc[mi][ni], 0, 0, 0);
    }

    // D mapping (m89/m91-verified): col = lane&15, row = q*4 + reg.
    if constexpr (OUT_MODE == 1){
        // bf16 out via LDS repack -> coalesced dwordx4 stores
        constexpr int RS = 136;          // u16 row stride (16B-aligned rows)
        #pragma unroll
        for (int ph = 0; ph < 2; ++ph){
            __syncthreads();
            if (wr == ph){
                #pragma unroll
                for (int mi = 0; mi < 4; mi++){
                    #pragma unroll
                    for (int i = 0; i < 4; i++){
                        int lr = mi * 16 + q * 4 + i;
                        float bm = 0.f;
                        if constexpr (BIAS_MODE == 1) bm = bias[m0 + ph * 64 + lr];
                        #pragma unroll
                        for (int ni = 0; ni < 4; ni++){
                            float v = acc[mi][ni][i] + bm;
                            if constexpr (RELU) v = (v > 0.f) ? v : 0.f;
                            sh[lr * RS + wc * 64 + ni * 16 + t] = f2bf(v);
                        }
                    }
                }
            }
            __syncthreads();
            #pragma unroll
            for (int j = 0; j < 4; j++){
                int c = tid + j * 256;          // 1024 chunks of 16B
                int lr = c >> 4, pos = c & 15;
                int m = m0 + ph * 64 + lr;
                *reinterpret_cast<uint4*>((u16*)Cp + (size_t)m * ldc + n0 + pos * 8) =
                    *reinterpret_cast<const uint4*>(&sh[lr * RS + pos * 8]);
            }
        }
    } else {
        #pragma unroll
        for (int mi = 0; mi < 4; mi++){
            #pragma unroll
            for (int i = 0; i < 4; i++){
                int m = m0 + wr * 64 + mi * 16 + q * 4 + i;
                float bm = 0.f;
                if constexpr (BIAS_MODE == 1) bm = bias[m];
                #pragma unroll
                for (int ni = 0; ni < 4; ni++){
                    int n = n0 + wc * 64 + ni * 16 + t;
                    float v = acc[mi][ni][i] + bm;
                    if constexpr (BIAS_MODE == 2) v += bias[n];
                    if constexpr (RELU) v = (v > 0.f) ? v : 0.f;
                    size_t ci = cofs + (size_t)m * ldc + n;
                    if constexpr (OUT_MODE == 2) atomicAdd(((float*)Cp) + ci, v);
                    else                         ((float*)Cp)[ci] = v;
                }
            }
        }
    }
}

// means[slot][q] = bf16( sums[slot][k*1024+q] / count[slot] ), k = slot>>7
__global__ void build_means(const float* sums, const float* counts, u16* means)
{
    int slot = blockIdx.x;               // 0..383
    int k = slot >> 7;
    float c = counts[slot];
    float inv = (c > 0.f) ? 1.f / c : 0.f;
    const float* src = sums + (size_t)slot * 3072 + (size_t)k * 1024;
    u16* dst = means + (size_t)slot * 1024;
    #pragma unroll
    for (int i = 0; i < 4; i++){
        int qi = threadIdx.x + i * 256;
        dst[qi] = f2bf(src[qi] * inv);
    }
}

// overflow means for ALL 3 branches of each overflow slot
__global__ void build_means_ovf(const float* sums, const float* counts, u16* mo)
{
    int b = blockIdx.x;                  // 0..383 : bb = branch, os = ovf slot
    int bb = b >> 7, os = b & 127;
    int slot = 384 + os;
    float c = counts[slot];
    float inv = (c > 0.f) ? 1.f / c : 0.f;
    const float* src = sums + (size_t)slot * 3072 + (size_t)bb * 1024;
    u16* dst = mo + (size_t)b * 1024;
    #pragma unroll
    for (int i = 0; i < 4; i++){
        int qi = threadIdx.x + i * 256;
        dst[qi] = f2bf(src[qi] * inv);
    }
}

__global__ void select_out(const float* outA, const float* outOvf,
                           const int* labels, const int* slot_of_node,
                           void* dout, const int* flags)
{
    int idx = blockIdx.x * 256 + threadIdx.x;   // < 300*1024
    int n = idx >> 10, r = idx & 1023;
    int slot = slot_of_node[n];
    float v;
    if (slot < 384) v = outA[(size_t)slot * 1024 + r];
    else {
        int k = labels[n];
        v = outOvf[((size_t)k * 128 + (slot - 384)) * 1024 + r];
    }
    if (flags[0]) ((u16*)dout)[idx] = f2bf(v);
    else          ((float*)dout)[idx] = v;
}

// ---------------------------------------------------------------------------
extern "C" void kernel_launch(void* const* d_in, const int* in_sizes, int n_in,
                              void* d_out, int out_size, void* d_ws, size_t ws_size,
                              hipStream_t stream)
{
    constexpr int C = 256, R = 1024, NN = 300, P = 40000;
    constexpr int PPAD = 40064;          // 313 * 128
    constexpr int M1 = 3 * R;            // 3072 L1 output rows (k-major)
    constexpr int SLOTS = 512;           // 3*128 grouped + 128 overflow

    const void* x      = d_in[0];
    const void* masks  = d_in[1];
    const int*  labels = (const int*)d_in[2];
    const void* W1[3] = { d_in[3], d_in[7],  d_in[11] };
    const void* B1[3] = { d_in[4], d_in[8],  d_in[12] };
    const void* W2[3] = { d_in[5], d_in[9],  d_in[13] };
    const void* B2[3] = { d_in[6], d_in[10], d_in[14] };
    (void)in_sizes; (void)n_in; (void)out_size;

    char* ws = (char*)d_ws;
    size_t off = 0;
    auto alloc = [&](size_t b)->size_t {
        size_t o = off; off += (b + 255) & ~(size_t)255; return o;
    };

    int*   flags   = (int*)  (ws + alloc(256));
    int*   slotmap = (int*)  (ws + alloc(384 * 4));
    int*   ovfflag = (int*)  (ws + alloc(256));
    u16*   feat    = (u16*)  (ws + alloc((size_t)PPAD * C * 2));    // [p][c]
    u16*   B1T     = (u16*)  (ws + alloc((size_t)M1 * C * 2));      // [k*R+r][c]
    float* b1f     = (float*)(ws + alloc((size_t)M1 * 4));
    float* b2f     = (float*)(ws + alloc((size_t)M1 * 4));
    u16*   mfT     = (u16*)  (ws + alloc((size_t)SLOTS * PPAD * 2));// [slot][p]
    float* sums    = (float*)(ws + alloc((size_t)SLOTS * M1 * 4));  // [slot][3072]
    float* counts  = (float*)(ws + alloc((size_t)SLOTS * 4));
    u16*   means   = (u16*)  (ws + alloc((size_t)384 * R * 2));     // [slot][q]
    u16*   meansOv = (u16*)  (ws + alloc((size_t)384 * R * 2));     // [b*128+os][q]
    u16*   W2T     = (u16*)  (ws + alloc((size_t)3 * R * R * 2));   // [k][r][q]
    float* outA    = (float*)(ws + alloc((size_t)384 * R * 4));     // [slot][r]
    float* outOvf  = (float*)(ws + alloc((size_t)384 * R * 4));     // [b*128+os][r]
    u16*   HT      = (u16*)  (ws + off);                            // [3072][cols]

    size_t remain  = (ws_size > off) ? ws_size - off : 0;
    long   maxcols = (long)(remain / ((size_t)M1 * 2));
    maxcols &= ~(long)127;
    if (maxcols > PPAD) maxcols = PPAD;
    if (maxcols < 128)  maxcols = 128;

    probe_dtypes<<<1, 64, 0, stream>>>(x, masks, flags);
    build_perm<<<1, 320, 0, stream>>>(labels, slotmap, ovfflag);
    hipMemsetAsync(mfT,  0, (size_t)SLOTS * PPAD * 2, stream);
    hipMemsetAsync(sums, 0, (size_t)SLOTS * M1 * 4, stream);

    trans_cvt_f3<<<dim3(PPAD / 32, C / 32, 1), dim3(32, 8), 0, stream>>>(
        x, x, x, feat, 0, C, P, C, flags);
    trans_cvt_f3<<<dim3(R / 32, C / 32, 3), dim3(32, 8), 0, stream>>>(
        W1[0], W1[1], W1[2], B1T, (size_t)R * C, C, R, C, flags);
    trans_cvt_f3<<<dim3(R / 32, R / 32, 3), dim3(32, 8), 0, stream>>>(
        W2[0], W2[1], W2[2], W2T, (size_t)R * R, R, R, R, flags);
    pack_biases<<<(3 * R + 255) / 256, 256, 0, stream>>>(
        B1[0], B1[1], B1[2], B2[0], B2[1], B2[2], b1f, b2f, flags);
    trans_mask<<<dim3(PPAD / 32, 384 / 32, 1), dim3(32, 8), 0, stream>>>(
        masks, mfT, slotmap, P, NN, PPAD, flags);
    count_rows<<<SLOTS, 256, 0, stream>>>(mfT, counts, PPAD, PPAD);

    for (long base = 0; base < PPAD; base += maxcols){
        long cols = PPAD - base; if (cols > maxcols) cols = maxcols;
        int iters = (int)(cols / 32);
        // L1: HT[m][p] = relu(B1T . feat^T + b1).  MAP=1: m-tile fastest so
        // consecutive blocks share the feat tile; B1T (1.5MB) stays L2-resident.
        gemm_nt<1, true, 1, 1>
            <<<dim3(M1 / 128, cols / 128, 1), 256, 0, stream>>>(
                B1T, C, feat + (size_t)base * C, C, HT, (int)cols, b1f,
                C / 32, C / 32, nullptr, 0, 0, 0, 0);
        // grouped mask-sum: block-diagonal restriction (3x less work)
        int S = 24; if (S > iters) S = iters;
        int kch = (iters + S - 1) / S;
        gemm_nt<0, false, 2, 2>
            <<<dim3(24, 1, S), 256, 0, stream>>>(
                mfT + base, PPAD, HT, (int)cols, sums, M1, nullptr,
                iters, kch, nullptr, 0, 0, 0, 0);
        // overflow nodes (rank>=128): dense vs all 3072 rows; skipped when none
        int S2 = 8; if (S2 > iters) S2 = iters;
        int kch2 = (iters + S2 - 1) / S2;
        gemm_nt<0, false, 2, 0>
            <<<dim3(24, 1, S2), 256, 0, stream>>>(
                mfT + (size_t)384 * PPAD + base, PPAD, HT, (int)cols,
                sums + (size_t)384 * M1, M1, nullptr,
                iters, kch2, ovfflag, 0, 0, 0, 0);
    }

    build_means<<<384, 256, 0, stream>>>(sums, counts, means);
    build_means_ovf<<<384, 256, 0, stream>>>(sums, counts, meansOv);

    // L2 on means, all 3 branches in one batched launch (blockIdx.z = branch)
    gemm_nt<2, false, 0, 3>
        <<<dim3(R / 128, 1, 3), 256, 0, stream>>>(
            means, R, W2T, R, outA, R, b2f,
            R / 32, R / 32, nullptr,
            (long)128 * R, (long)R * R, (long)128 * R, (long)R);
    // overflow L2 (skipped when no overflow)
    gemm_nt<2, false, 0, 3>
        <<<dim3(R / 128, 1, 3), 256, 0, stream>>>(
            meansOv, R, W2T, R, outOvf, R, b2f,
            R / 32, R / 32, ovfflag,
            (long)128 * R, (long)R * R, (long)128 * R, (long)R);

    select_out<<<(NN * R) / 256, 256, 0, stream>>>(
        outA, outOvf, labels, slotmap, d_out, flags);
}

// Round 3
// 451.651 us; speedup vs baseline: 1.5961x; 1.3228x over previous
//
#include <hip/hip_runtime.h>

typedef unsigned short u16;
typedef unsigned int   u32;

using bf16x8 = __attribute__((ext_vector_type(8))) __bf16;
using f32x4  = __attribute__((ext_vector_type(4))) float;

__device__ __forceinline__ float bf2f(u16 h){ return __uint_as_float(((u32)h) << 16); }
__device__ __forceinline__ u16 f2bf(float f){
    u32 u = __float_as_uint(f);
    u32 r = u + 0x7FFFu + ((u >> 16) & 1u);   // round-to-nearest-even
    return (u16)(r >> 16);
}

// async global->LDS, 16B per lane; LDS dest = wave-uniform base + lane*16.
__device__ __forceinline__ void async16(const void* g, void* l){
    __builtin_amdgcn_global_load_lds(
        (const __attribute__((address_space(1))) unsigned int*)g,
        (__attribute__((address_space(3))) unsigned int*)l, 16, 0, 0);
}

// ---------------------------------------------------------------------------
// dtype probe: flags[0]=1 if float tensors bf16 else fp32; flags[1]=mask dtype
// 0=u8/bool,1=i32,2=bf16,3=f32.
// ---------------------------------------------------------------------------
__global__ void probe_dtypes(const void* x, const void* masks, int* flags)
{
    if (blockIdx.x != 0 || threadIdx.x != 0) return;
    const u16* hx = (const u16*)x;
    int cnt = 0;
    for (int i = 0; i < 128; i++){
        int e = (hx[i] >> 7) & 0xFF;
        if (e >= 100 && e <= 140) cnt++;
    }
    flags[0] = (cnt >= 100) ? 1 : 0;

    const u32* w  = (const u32*)masks;
    const u16* hm = (const u16*)masks;
    int i32ok = 1, f32ok = 1, bf16ok = 1;
    for (int i = 0; i < 64; i++){
        u32 v = w[i];
        if (v > 1u) i32ok = 0;
        if (v != 0u && v != 0x3F800000u) f32ok = 0;
    }
    for (int i = 0; i < 128; i++){
        u16 h = hm[i];
        if (h != 0 && h != 0x3F80) bf16ok = 0;
    }
    int md = 0;
    if (i32ok) md = 1; else if (f32ok) md = 3; else if (bf16ok) md = 2;
    flags[1] = md;
}

// ---------------------------------------------------------------------------
// Label grouping: slot_of_node[n] = label*128 + rank (rank<128), else
// 384 + overflow_rank. ovf_flag = #overflow nodes (0 in the expected case).
// ---------------------------------------------------------------------------
__global__ void build_perm(const int* labels, int* slot_of_node, int* ovf_flag)
{
    __shared__ int lab[300];
    __shared__ unsigned char sp[300];
    int t = threadIdx.x;
    if (t < 300) lab[t] = labels[t];
    __syncthreads();
    int r = 0;
    if (t < 300){
        int k = lab[t];
        for (int j = 0; j < t; j++) r += (lab[j] == k);
        sp[t] = (r >= 128) ? 1 : 0;
    }
    __syncthreads();
    if (t < 300){
        if (!sp[t]) slot_of_node[t] = lab[t] * 128 + r;
        else {
            int so = 0;
            for (int j = 0; j < t; j++) so += sp[j];
            slot_of_node[t] = 384 + so;
        }
    }
    if (t == 0){
        int tot = 0;
        for (int j = 0; j < 300; j++) tot += sp[j];
        *ovf_flag = tot;
    }
}

// ---------------------------------------------------------------------------
// Transpose + convert to bf16, 3 sources via blockIdx.z; zero-pads j >= J.
// ---------------------------------------------------------------------------
__global__ void trans_cvt_f3(const void* s0, const void* s1, const void* s2,
                             u16* dst, size_t dstride, int I, int J, int ldd,
                             const int* flags)
{
    __shared__ float tile[32][33];
    const void* src = (blockIdx.z == 0) ? s0 : (blockIdx.z == 1) ? s1 : s2;
    u16* d = dst + (size_t)blockIdx.z * dstride;
    int j0 = blockIdx.x * 32, i0 = blockIdx.y * 32;
    int tx = threadIdx.x, ty = threadIdx.y;
    bool isbf = (flags[0] != 0);
    #pragma unroll
    for (int s = 0; s < 32; s += 8){
        int i = i0 + ty + s, j = j0 + tx;
        float v = 0.f;
        if (j < J){
            size_t idx = (size_t)i * J + j;
            v = isbf ? bf2f(((const u16*)src)[idx]) : ((const float*)src)[idx];
        }
        tile[ty + s][tx] = v;
    }
    __syncthreads();
    #pragma unroll
    for (int s = 0; s < 32; s += 8){
        int j = j0 + ty + s, i = i0 + tx;
        d[(size_t)j * ldd + i] = f2bf(tile[tx][ty + s]);
    }
}

// masks [P][NN] -> mfT[slot][p] bf16 {0,1}, rows permuted by slot_of_node.
__global__ void trans_mask(const void* src, u16* dst, const int* slot_of_node,
                           int P_, int NN_, int ldd, const int* flags)
{
    __shared__ u16 tile[32][33];
    __shared__ int slt[32];
    int p0 = blockIdx.x * 32, n0 = blockIdx.y * 32;
    int tx = threadIdx.x, ty = threadIdx.y;
    int md = flags[1];
    if (ty == 0){
        int n = n0 + tx;
        slt[tx] = (n < NN_) ? slot_of_node[n] : -1;
    }
    #pragma unroll
    for (int s = 0; s < 32; s += 8){
        int p = p0 + ty + s, n = n0 + tx;
        u16 v = 0;
        if (p < P_ && n < NN_){
            size_t idx = (size_t)p * NN_ + n;
            bool on;
            if (md == 0)      on = ((const unsigned char*)src)[idx] != 0;
            else if (md == 1) on = ((const int*)src)[idx] != 0;
            else if (md == 2) on = ((const u16*)src)[idx] != 0;
            else              on = ((const float*)src)[idx] != 0.f;
            v = on ? (u16)0x3F80 : (u16)0;
        }
        tile[ty + s][tx] = v;
    }
    __syncthreads();
    #pragma unroll
    for (int s = 0; s < 32; s += 8){
        int slot = slt[ty + s];
        int p = p0 + tx;
        if (slot >= 0 && p < ldd)
            dst[(size_t)slot * ldd + p] = tile[tx][ty + s];
    }
}

__global__ void pack_biases(const void* a0, const void* a1, const void* a2,
                            const void* c0, const void* c1, const void* c2,
                            float* b1f, float* b2f, const int* flags)
{
    int idx = blockIdx.x * 256 + threadIdx.x;
    if (idx >= 3072) return;
    int k = idx >> 10, r = idx & 1023;
    bool isbf = (flags[0] != 0);
    const void* p1 = (k == 0) ? a0 : (k == 1) ? a1 : a2;
    const void* p2 = (k == 0) ? c0 : (k == 1) ? c1 : c2;
    b1f[idx] = isbf ? bf2f(((const u16*)p1)[r]) : ((const float*)p1)[r];
    b2f[idx] = isbf ? bf2f(((const u16*)p2)[r]) : ((const float*)p2)[r];
}

__global__ void count_rows(const u16* mfT, float* counts, int ldd, int Pfull)
{
    int n = blockIdx.x;
    const u16* row = mfT + (size_t)n * ldd;
    int s = 0;
    for (int p = threadIdx.x; p < Pfull; p += 256) s += (row[p] != 0);
    __shared__ int red[256];
    red[threadIdx.x] = s;
    __syncthreads();
    for (int st = 128; st > 0; st >>= 1){
        if (threadIdx.x < st) red[threadIdx.x] += red[threadIdx.x + st];
        __syncthreads();
    }
    if (threadIdx.x == 0) counts[n] = (float)red[0];
}

// ---------------------------------------------------------------------------
// FUSED L1 + mask-sum. Per block: m-tile (128 of 3072 L1 rows, branch=bx>>3)
// x chunk of 128-pixel tiles. Per p-tile:
//   stage-1: H = relu(B1T[m-tile] . feat[p-tile]^T + b1)  (K=256, acc in regs)
//   repack:  H -> LDS Hs[pc][m][32], column-group XOR-swizzled by (m>>2)&3
//   stage-2: acc2[slot][m] += mask[slot][p-tile] . H^T  (K=128; mask A-frags
//            loaded global->regs as dwordx4 -- no mask LDS)
// End: one atomicAdd dump of acc2.
// MAP 0: grouped slots (branch diagonal), sums = [3*128][1024]
// MAP 1: overflow slots (row 384+), sums = [128][3072]; skip when !*skipf
// ---------------------------------------------------------------------------
template<int MAP>
__global__ __launch_bounds__(256, 2)
void fused_l1_mask(const u16* __restrict__ B1T, const u16* __restrict__ feat,
                   const u16* __restrict__ mfT, const float* __restrict__ b1f,
                   float* __restrict__ sums, int tilesPerChunk,
                   const int* __restrict__ skipf)
{
    if constexpr (MAP == 1){ if (*skipf == 0) return; }
    constexpr int PPAD = 40064;
    __shared__ __align__(16) u16 As[4096];    // B1T k-chunk staging (8 KB)
    __shared__ __align__(16) u16 Bs[4096];    // feat k-chunk staging (8 KB)
    __shared__ __align__(16) u16 Hs[16384];   // H tile, [pc][128][32] (32 KB)

    const int tid = threadIdx.x;
    const int wave = tid >> 6, lane = tid & 63;
    const int wr = wave >> 1, wc = wave & 1;
    const int t = lane & 15, q = lane >> 4;
    const int bx = blockIdx.x;                // m-tile 0..23
    const int m0 = bx * 128;
    const int srow = (MAP == 0) ? ((bx >> 3) * 128) : 384;

    int ts = blockIdx.y * tilesPerChunk;
    int te = ts + tilesPerChunk; if (te > 313) te = 313;
    if (ts >= te) return;

    float bv[4][4];
    #pragma unroll
    for (int mi = 0; mi < 4; mi++)
        #pragma unroll
        for (int i = 0; i < 4; i++)
            bv[mi][i] = b1f[m0 + wr*64 + mi*16 + q*4 + i];

    const int cr = lane >> 2, cp = lane & 3;
    const int ca = wave*2, cb = wave*2+1;
    const u16* gA0 = B1T + (size_t)(m0 + ca*16 + cr)*256 + cp*8;
    const u16* gA1 = B1T + (size_t)(m0 + cb*16 + cr)*256 + cp*8;
    u16* lA0 = As + ca*512;  u16* lA1 = As + cb*512;
    u16* lB0 = Bs + ca*512;  u16* lB1 = Bs + cb*512;
    const u16* mrow = mfT + (size_t)(srow + wr*64 + t) * PPAD;  // + mi*16*PPAD

    f32x4 acc2[4][4];
    #pragma unroll
    for (int a = 0; a < 4; a++)
        #pragma unroll
        for (int b = 0; b < 4; b++)
            #pragma unroll
            for (int e = 0; e < 4; e++) acc2[a][b][e] = 0.f;

    for (int pt = ts; pt < te; ++pt){
        const int p0 = pt * 128;
        const u16* gB0 = feat + (size_t)(p0 + ca*16 + cr)*256 + cp*8;
        const u16* gB1 = feat + (size_t)(p0 + cb*16 + cr)*256 + cp*8;

        f32x4 acc1[4][4];
        #pragma unroll
        for (int a = 0; a < 4; a++)
            #pragma unroll
            for (int b = 0; b < 4; b++)
                #pragma unroll
                for (int e = 0; e < 4; e++) acc1[a][b][e] = 0.f;

        #pragma unroll
        for (int kt = 0; kt < 8; ++kt){
            __syncthreads();
            const size_t ko = (size_t)kt * 32;
            async16(gA0 + ko, lA0);
            async16(gA1 + ko, lA1);
            async16(gB0 + ko, lB0);
            async16(gB1 + ko, lB1);
            __syncthreads();
            bf16x8 af[4], bg[4];
            #pragma unroll
            for (int mi = 0; mi < 4; mi++)
                af[mi] = *reinterpret_cast<const bf16x8*>(
                    &As[(wr*64 + mi*16 + t)*32 + q*8]);
            #pragma unroll
            for (int ni = 0; ni < 4; ni++)
                bg[ni] = *reinterpret_cast<const bf16x8*>(
                    &Bs[(wc*64 + ni*16 + t)*32 + q*8]);
            #pragma unroll
            for (int mi = 0; mi < 4; mi++)
                #pragma unroll
                for (int ni = 0; ni < 4; ni++)
                    acc1[mi][ni] = __builtin_amdgcn_mfma_f32_16x16x32_bf16(
                        af[mi], bg[ni], acc1[mi][ni], 0, 0, 0);
        }

        // epilogue: bias+relu, write H to Hs with XOR swizzle.
        // D map: m_l = wr*64+mi*16+q*4+i (so (m_l>>2)&3 == q), p_l = wc*64+ni*16+t
        #pragma unroll
        for (int mi = 0; mi < 4; mi++){
            #pragma unroll
            for (int i = 0; i < 4; i++){
                const int m_l = wr*64 + mi*16 + q*4 + i;
                const float bb = bv[mi][i];
                #pragma unroll
                for (int ni = 0; ni < 4; ni++){
                    const int p_l = wc*64 + ni*16 + t;
                    float v = acc1[mi][ni][i] + bb;
                    v = (v > 0.f) ? v : 0.f;
                    const int pc = p_l >> 5, pin = p_l & 31;
                    const int cg = (pin >> 3) ^ q;     // swizzle by (m_l>>2)&3
                    Hs[pc*4096 + m_l*32 + cg*8 + (pin & 7)] = f2bf(v);
                }
            }
        }
        __syncthreads();

        // stage-2: sums[slot][m] += mask . H^T, K = 128 pixels (4 chunks)
        #pragma unroll
        for (int pc = 0; pc < 4; ++pc){
            bf16x8 ma[4], hb[4];
            #pragma unroll
            for (int mi = 0; mi < 4; mi++)
                ma[mi] = *reinterpret_cast<const bf16x8*>(
                    mrow + (size_t)(mi*16)*PPAD + p0 + pc*32 + q*8);
            #pragma unroll
            for (int ni = 0; ni < 4; ni++){
                const int row = wc*64 + ni*16 + t;
                hb[ni] = *reinterpret_cast<const bf16x8*>(
                    &Hs[pc*4096 + row*32 + ((q ^ (t >> 2)) * 8)]);
            }
            #pragma unroll
            for (int mi = 0; mi < 4; mi++)
                #pragma unroll
                for (int ni = 0; ni < 4; ni++)
                    acc2[mi][ni] = __builtin_amdgcn_mfma_f32_16x16x32_bf16(
                        ma[mi], hb[ni], acc2[mi][ni], 0, 0, 0);
        }
    }

    // dump: C rows = slots, cols = m
    #pragma unroll
    for (int mi = 0; mi < 4; mi++){
        #pragma unroll
        for (int i = 0; i < 4; i++){
            const int slot_l = wr*64 + mi*16 + q*4 + i;
            #pragma unroll
            for (int ni = 0; ni < 4; ni++){
                const int m_l = wc*64 + ni*16 + t;
                const float v = acc2[mi][ni][i];
                if constexpr (MAP == 0)
                    atomicAdd(sums + (size_t)((bx>>3)*128 + slot_l)*1024
                                   + (bx&7)*128 + m_l, v);
                else
                    atomicAdd(sums + (size_t)slot_l*3072 + bx*128 + m_l, v);
            }
        }
    }
}

// ---------------------------------------------------------------------------
// NT GEMM (round-2): used for the small L2 layers only (MAP==3 batched).
// ---------------------------------------------------------------------------
template<int BIAS_MODE, bool RELU, int OUT_MODE, int MAP>
__global__ __launch_bounds__(256)
void gemm_nt(const u16* __restrict__ A, int lda,
             const u16* __restrict__ B, int ldb,
             void* __restrict__ Cp, int ldc,
             const float* __restrict__ bias,
             int kIters, int kChunk,
             const int* __restrict__ skipf,
             long abatch, long bbatch, long cbatch, long bbias)
{
    if (skipf && *skipf == 0) return;
    __shared__ __align__(16) u16 sh[8704];
    u16* As = sh;
    u16* Bs = sh + 4096;

    const int tid  = threadIdx.x;
    const int wave = tid >> 6, lane = tid & 63;
    const int wr = wave >> 1, wc = wave & 1;
    const int t = lane & 15, q = lane >> 4;

    int m0, n0;
    if constexpr (MAP == 1){ m0 = blockIdx.x * 128; n0 = blockIdx.y * 128; }
    else if constexpr (MAP == 2){ m0 = (blockIdx.x >> 3) * 128; n0 = blockIdx.x * 128; }
    else { m0 = blockIdx.y * 128; n0 = blockIdx.x * 128; }

    size_t cofs = 0;
    int k0, k1;
    if constexpr (MAP == 3){
        const int bz = blockIdx.z;
        A += (size_t)bz * (size_t)abatch;
        B += (size_t)bz * (size_t)bbatch;
        bias += (size_t)bz * (size_t)bbias;
        cofs = (size_t)bz * (size_t)cbatch;
        k0 = 0; k1 = kIters;
    } else {
        k0 = blockIdx.z * kChunk;
        k1 = k0 + kChunk; if (k1 > kIters) k1 = kIters;
        if (k0 >= k1) return;
    }

    const int cr = lane >> 2, cp = lane & 3;
    const int ca = wave * 2, cb = wave * 2 + 1;
    const u16* gA0 = A + (size_t)(m0 + ca * 16 + cr) * lda + cp * 8;
    const u16* gA1 = A + (size_t)(m0 + cb * 16 + cr) * lda + cp * 8;
    const u16* gB0 = B + (size_t)(n0 + ca * 16 + cr) * ldb + cp * 8;
    const u16* gB1 = B + (size_t)(n0 + cb * 16 + cr) * ldb + cp * 8;
    u16* lA0 = As + ca * 512;  u16* lA1 = As + cb * 512;
    u16* lB0 = Bs + ca * 512;  u16* lB1 = Bs + cb * 512;

    f32x4 acc[4][4];
    #pragma unroll
    for (int a = 0; a < 4; a++)
        #pragma unroll
        for (int b = 0; b < 4; b++)
            #pragma unroll
            for (int e = 0; e < 4; e++) acc[a][b][e] = 0.f;

    for (int kt = k0; kt < k1; ++kt){
        __syncthreads();
        const size_t ko = (size_t)kt * 32;
        async16(gA0 + ko, lA0);
        async16(gA1 + ko, lA1);
        async16(gB0 + ko, lB0);
        async16(gB1 + ko, lB1);
        __syncthreads();
        bf16x8 af[4], bg[4];
        #pragma unroll
        for (int mi = 0; mi < 4; mi++)
            af[mi] = *reinterpret_cast<const bf16x8*>(
                &As[(wr * 64 + mi * 16 + t) * 32 + q * 8]);
        #pragma unroll
        for (int ni = 0; ni < 4; ni++)
            bg[ni] = *reinterpret_cast<const bf16x8*>(
                &Bs[(wc * 64 + ni * 16 + t) * 32 + q * 8]);
        #pragma unroll
        for (int mi = 0; mi < 4; mi++)
            #pragma unroll
            for (int ni = 0; ni < 4; ni++)
                acc[mi][ni] = __builtin_amdgcn_mfma_f32_16x16x32_bf16(
                    af[mi], bg[ni], acc[mi][ni], 0, 0, 0);
    }

    #pragma unroll
    for (int mi = 0; mi < 4; mi++){
        #pragma unroll
        for (int i = 0; i < 4; i++){
            int m = m0 + wr * 64 + mi * 16 + q * 4 + i;
            float bm = 0.f;
            if constexpr (BIAS_MODE == 1) bm = bias[m];
            #pragma unroll
            for (int ni = 0; ni < 4; ni++){
                int n = n0 + wc * 64 + ni * 16 + t;
                float v = acc[mi][ni][i] + bm;
                if constexpr (BIAS_MODE == 2) v += bias[n];
                if constexpr (RELU) v = (v > 0.f) ? v : 0.f;
                size_t ci = cofs + (size_t)m * ldc + n;
                if constexpr (OUT_MODE == 2) atomicAdd(((float*)Cp) + ci, v);
                else                         ((float*)Cp)[ci] = v;
            }
        }
    }
}

// means[slot][q] = bf16( sums3[slot][q] / counts[slot] )
__global__ void build_means(const float* sums3, const float* counts, u16* means)
{
    int slot = blockIdx.x;               // 0..383
    float c = counts[slot];
    float inv = (c > 0.f) ? 1.f / c : 0.f;
    const float* src = sums3 + (size_t)slot * 1024;
    u16* dst = means + (size_t)slot * 1024;
    #pragma unroll
    for (int i = 0; i < 4; i++){
        int qi = threadIdx.x + i * 256;
        dst[qi] = f2bf(src[qi] * inv);
    }
}

// overflow means for ALL 3 branches of each overflow slot
__global__ void build_means_ovf(const float* sumsOvf, const float* counts, u16* mo)
{
    int b = blockIdx.x;                  // bb = branch, os = ovf slot
    int bb = b >> 7, os = b & 127;
    float c = counts[384 + os];
    float inv = (c > 0.f) ? 1.f / c : 0.f;
    const float* src = sumsOvf + (size_t)os * 3072 + (size_t)bb * 1024;
    u16* dst = mo + (size_t)b * 1024;
    #pragma unroll
    for (int i = 0; i < 4; i++){
        int qi = threadIdx.x + i * 256;
        dst[qi] = f2bf(src[qi] * inv);
    }
}

__global__ void select_out(const float* outA, const float* outOvf,
                           const int* labels, const int* slot_of_node,
                           void* dout, const int* flags)
{
    int idx = blockIdx.x * 256 + threadIdx.x;   // < 300*1024
    int n = idx >> 10, r = idx & 1023;
    int slot = slot_of_node[n];
    float v;
    if (slot < 384) v = outA[(size_t)slot * 1024 + r];
    else {
        int k = labels[n];
        v = outOvf[((size_t)k * 128 + (slot - 384)) * 1024 + r];
    }
    if (flags[0]) ((u16*)dout)[idx] = f2bf(v);
    else          ((float*)dout)[idx] = v;
}

// ---------------------------------------------------------------------------
extern "C" void kernel_launch(void* const* d_in, const int* in_sizes, int n_in,
                              void* d_out, int out_size, void* d_ws, size_t ws_size,
                              hipStream_t stream)
{
    constexpr int C = 256, R = 1024, NN = 300, P = 40000;
    constexpr int PPAD = 40064;          // 313 * 128
    constexpr int M1 = 3 * R;            // 3072 L1 rows (branch-major)
    constexpr int SLOTS = 512;           // 3*128 grouped + 128 overflow

    const void* x      = d_in[0];
    const void* masks  = d_in[1];
    const int*  labels = (const int*)d_in[2];
    const void* W1[3] = { d_in[3], d_in[7],  d_in[11] };
    const void* B1[3] = { d_in[4], d_in[8],  d_in[12] };
    const void* W2[3] = { d_in[5], d_in[9],  d_in[13] };
    const void* B2[3] = { d_in[6], d_in[10], d_in[14] };
    (void)in_sizes; (void)n_in; (void)out_size; (void)ws_size;

    char* ws = (char*)d_ws;
    size_t off = 0;
    auto alloc = [&](size_t b)->size_t {
        size_t o = off; off += (b + 255) & ~(size_t)255; return o;
    };

    int*   flags   = (int*)  (ws + alloc(256));
    int*   slotmap = (int*)  (ws + alloc(384 * 4));
    int*   ovfflag = (int*)  (ws + alloc(256));
    u16*   feat    = (u16*)  (ws + alloc((size_t)PPAD * C * 2));    // [p][c]
    u16*   B1T     = (u16*)  (ws + alloc((size_t)M1 * C * 2));      // [m][c]
    float* b1f     = (float*)(ws + alloc((size_t)M1 * 4));
    float* b2f     = (float*)(ws + alloc((size_t)M1 * 4));
    u16*   mfT     = (u16*)  (ws + alloc((size_t)SLOTS * PPAD * 2));// [slot][p]
    float* sums3   = (float*)(ws + alloc((size_t)384 * 1024 * 4));  // [slot][m_in_branch]
    float* sumsOvf = (float*)(ws + alloc((size_t)128 * M1 * 4));    // [os][3072]
    float* counts  = (float*)(ws + alloc((size_t)SLOTS * 4));
    u16*   means   = (u16*)  (ws + alloc((size_t)384 * R * 2));     // [slot][q]
    u16*   meansOv = (u16*)  (ws + alloc((size_t)384 * R * 2));     // [bb*128+os][q]
    u16*   W2T     = (u16*)  (ws + alloc((size_t)3 * R * R * 2));   // [k][r][q]
    float* outA    = (float*)(ws + alloc((size_t)384 * R * 4));     // [slot][r]
    float* outOvf  = (float*)(ws + alloc((size_t)384 * R * 4));     // [bb*128+os][r]

    probe_dtypes<<<1, 64, 0, stream>>>(x, masks, flags);
    build_perm<<<1, 320, 0, stream>>>(labels, slotmap, ovfflag);
    hipMemsetAsync(mfT, 0, (size_t)SLOTS * PPAD * 2, stream);
    // sums3 and sumsOvf are contiguous (both 256B-aligned sizes): one memset
    hipMemsetAsync(sums3, 0, (size_t)384 * 1024 * 4 + (size_t)128 * M1 * 4, stream);

    trans_cvt_f3<<<dim3(PPAD / 32, C / 32, 1), dim3(32, 8), 0, stream>>>(
        x, x, x, feat, 0, C, P, C, flags);
    trans_cvt_f3<<<dim3(R / 32, C / 32, 3), dim3(32, 8), 0, stream>>>(
        W1[0], W1[1], W1[2], B1T, (size_t)R * C, C, R, C, flags);
    trans_cvt_f3<<<dim3(R / 32, R / 32, 3), dim3(32, 8), 0, stream>>>(
        W2[0], W2[1], W2[2], W2T, (size_t)R * R, R, R, R, flags);
    pack_biases<<<(3 * R + 255) / 256, 256, 0, stream>>>(
        B1[0], B1[1], B1[2], B2[0], B2[1], B2[2], b1f, b2f, flags);
    trans_mask<<<dim3(PPAD / 32, 384 / 32, 1), dim3(32, 8), 0, stream>>>(
        masks, mfT, slotmap, P, NN, PPAD, flags);
    count_rows<<<SLOTS, 256, 0, stream>>>(mfT, counts, PPAD, PPAD);

    // fused L1 + mask-sum (grid x-fastest: all 24 m-tiles share feat p-tiles
    // through L2). 24 x 22 = 528 blocks, 2 blocks/CU, 15 p-tiles per chain.
    fused_l1_mask<0><<<dim3(24, 22), 256, 0, stream>>>(
        B1T, feat, mfT, b1f, sums3, 15, nullptr);
    // overflow path (skipped unless some label has > 128 nodes)
    fused_l1_mask<1><<<dim3(24, 8), 256, 0, stream>>>(
        B1T, feat, mfT, b1f, sumsOvf, 40, ovfflag);

    build_means<<<384, 256, 0, stream>>>(sums3, counts, means);
    build_means_ovf<<<384, 256, 0, stream>>>(sumsOvf, counts, meansOv);

    // L2 on means, all 3 branches batched via blockIdx.z
    gemm_nt<2, false, 0, 3>
        <<<dim3(R / 128, 1, 3), 256, 0, stream>>>(
            means, R, W2T, R, outA, R, b2f,
            R / 32, R / 32, nullptr,
            (long)128 * R, (long)R * R, (long)128 * R, (long)R);
    gemm_nt<2, false, 0, 3>
        <<<dim3(R / 128, 1, 3), 256, 0, stream>>>(
            meansOv, R, W2T, R, outOvf, R, b2f,
            R / 32, R / 32, ovfflag,
            (long)128 * R, (long)R * R, (long)128 * R, (long)R);

    select_out<<<(NN * R) / 256, 256, 0, stream>>>(
        outA, outOvf, labels, slotmap, d_out, flags);
}